// Round 5
// baseline (106.197 us; speedup 1.0000x reference)
//
#include <hip/hip_runtime.h>
#include <math.h>

#define T_ 16
#define B_ 16
#define C_ 8
#define H_ 128
#define W_ 128
#define HW_ (H_*W_)
#define CHW_ (C_*HW_)
#define NSL 16                       // 16 slices of 8 rows
#define SRW 8                        // rows per slice
#define TS 8                         // t-chunk length (2 chunks)
#define NV 19                        // 0..7 sumc, 8..15 maxc, 16 dsum, 17 m1, 18 m2

__device__ __forceinline__ float wave_sum(float v){
    #pragma unroll
    for (int o=32;o>0;o>>=1) v += __shfl_down(v,o,64);
    return v;
}
__device__ __forceinline__ float wave_max(float v){
    #pragma unroll
    for (int o=32;o>0;o>>=1) v = fmaxf(v,__shfl_down(v,o,64));
    return v;
}

// ---------------- K1: read-once statistics ----------------
// Block = (b, slice of 8 rows, t-half). Loops 8 timesteps; previous frame's
// values stay in registers (px) so the prev-frame re-read is eliminated.
// Per t: load own row float4 x 8ch (+64 threads load halo y rows), build
// channel-sum y in LDS, 3x3 box filter -> m1, per-t block reduce -> partials.
__global__ __launch_bounds__(256, 2) void stats_kernel(
    const float* __restrict__ events, float* __restrict__ partials)
{
    int bid  = blockIdx.x;
    int half = bid & 1;
    int s    = (bid >> 1) & 15;
    int b    = bid >> 5;
    int t0   = half * TS;
    int h0   = s * SRW;
    int tid  = threadIdx.x;

    int col4 = tid & 31, c0 = col4 * 4;
    int r    = tid >> 5;              // own row 0..7
    int gh   = h0 + r;

    __shared__ float yb[SRW+2][W_];   // y rows h0-1 .. h0+8
    __shared__ float red[4][NV];

    // halo job (tid<64): hsel 0 -> row h0-1, 1 -> row h0+8
    int  hsel = tid >> 5;
    int  hgh  = h0 + (hsel ? SRW : -1);
    bool hok  = (tid < 64) && (hgh >= 0) && (hgh < H_);

    const size_t fstride = (size_t)B_ * CHW_;
    const float* own0  = events + (size_t)(t0*B_+b)*CHW_ + gh*W_  + c0;
    const float* halo0 = events + (size_t)(t0*B_+b)*CHW_ + hgh*W_ + c0;

    float4 cx[C_], px[C_], hx[C_], cx2[C_];

    #pragma unroll
    for (int c=0;c<C_;c++) cx[c] = *reinterpret_cast<const float4*>(own0 + c*HW_);
    if (hok){
        #pragma unroll
        for (int c=0;c<C_;c++) hx[c] = *reinterpret_cast<const float4*>(halo0 + c*HW_);
    }
    if (half){   // prev frame (t0-1) for dsum at first t of chunk
        const float* pv = own0 - fstride;
        #pragma unroll
        for (int c=0;c<C_;c++) px[c] = *reinterpret_cast<const float4*>(pv + c*HW_);
    } else {
        #pragma unroll
        for (int c=0;c<C_;c++){ px[c].x=0.f; px[c].y=0.f; px[c].z=0.f; px[c].w=0.f; }
    }

    float cnt0 = (c0==0)     ? 2.f : 3.f;
    float cnt3 = (c0+3==W_-1)? 2.f : 3.f;
    float cnth = (gh==0 || gh==H_-1) ? 2.f : 3.f;

    #pragma unroll 1
    for (int tt=0; tt<TS; ++tt){
        int t = t0 + tt;

        // ---- phase A: consume cx/hx, write y rows, per-thread stats ----
        float sumc[C_], maxc[C_];
        float4 y; y.x=0.f; y.y=0.f; y.z=0.f; y.w=0.f;
        float q0=0.f,q1=0.f,q2=0.f,q3=0.f;
        float dsum = 0.f;
        #pragma unroll
        for (int c=0;c<C_;c++){
            float4 x = cx[c];
            y.x+=x.x; y.y+=x.y; y.z+=x.z; y.w+=x.w;
            q0=fmaf(x.x,x.x,q0); q1=fmaf(x.y,x.y,q1);
            q2=fmaf(x.z,x.z,q2); q3=fmaf(x.w,x.w,q3);
            sumc[c] = (x.x+x.y)+(x.z+x.w);
            maxc[c] = fmaxf(fmaxf(x.x,x.y),fmaxf(x.z,x.w));
        }
        float m2 = cnth * (q0*cnt0 + (q1+q2)*3.f + q3*cnt3);
        if (t > 0){
            #pragma unroll
            for (int c=0;c<C_;c++){
                float4 x = cx[c], p = px[c];
                dsum += fabsf(x.x-p.x)+fabsf(x.y-p.y)
                      + fabsf(x.z-p.z)+fabsf(x.w-p.w);
            }
        }
        #pragma unroll
        for (int c=0;c<C_;c++) px[c] = cx[c];

        *reinterpret_cast<float4*>(&yb[r+1][c0]) = y;
        if (tid < 64){
            float4 hy; hy.x=0.f; hy.y=0.f; hy.z=0.f; hy.w=0.f;
            if (hok){
                #pragma unroll
                for (int c=0;c<C_;c++){
                    float4 x = hx[c];
                    hy.x+=x.x; hy.y+=x.y; hy.z+=x.z; hy.w+=x.w;
                }
            }
            *reinterpret_cast<float4*>(&yb[hsel ? SRW+1 : 0][c0]) = hy;
        }
        __syncthreads();

        // ---- prefetch t+1 (overlaps phase B) ----
        {
            int tn = (tt+1 < TS) ? (tt+1) : tt;     // clamp (last iter reloads)
            const float* op = own0 + (size_t)tn*fstride;
            #pragma unroll
            for (int c=0;c<C_;c++) cx2[c] = *reinterpret_cast<const float4*>(op + c*HW_);
            if (hok){
                const float* hp = halo0 + (size_t)tn*fstride;
                #pragma unroll
                for (int c=0;c<C_;c++) hx[c] = *reinterpret_cast<const float4*>(hp + c*HW_);
            }
        }

        // ---- phase B: 3x3 box filter of y -> m1 ----
        float m1;
        {
            float4 v0 = *reinterpret_cast<const float4*>(&yb[r  ][c0]);
            float4 v1 = *reinterpret_cast<const float4*>(&yb[r+1][c0]);
            float4 v2 = *reinterpret_cast<const float4*>(&yb[r+2][c0]);
            float4 vv; vv.x=v0.x+v1.x+v2.x; vv.y=v0.y+v1.y+v2.y;
                       vv.z=v0.z+v1.z+v2.z; vv.w=v0.w+v1.w+v2.w;
            float vL = (c0>0)      ? yb[r][c0-1]+yb[r+1][c0-1]+yb[r+2][c0-1] : 0.f;
            float vR = (c0+4<W_)   ? yb[r][c0+4]+yb[r+1][c0+4]+yb[r+2][c0+4] : 0.f;
            float s1x = vL  +vv.x+vv.y;
            float s1y = vv.x+vv.y+vv.z;
            float s1z = vv.y+vv.z+vv.w;
            float s1w = vv.z+vv.w+vR;
            m1 = s1x*s1x + s1y*s1y + s1z*s1z + s1w*s1w;
        }

        // ---- per-t block reduce of 19 values ----
        float vals[NV];
        #pragma unroll
        for (int c=0;c<C_;c++){ vals[c]=sumc[c]; vals[8+c]=maxc[c]; }
        vals[16]=dsum; vals[17]=m1; vals[18]=m2;

        int lane = tid & 63, wv = tid >> 6;
        #pragma unroll
        for (int i=0;i<NV;i++){
            float rr = (i>=8 && i<16) ? wave_max(vals[i]) : wave_sum(vals[i]);
            if (lane==0) red[wv][i] = rr;
        }
        __syncthreads();          // red ready; also protects yb for next t
        if (tid < NV){
            float a = red[0][tid], b2 = red[1][tid], c = red[2][tid], d = red[3][tid];
            float rr = (tid>=8 && tid<16) ? fmaxf(fmaxf(a,b2),fmaxf(c,d)) : ((a+b2)+(c+d));
            partials[((size_t)(t*B_+b)*NSL + s)*NV + tid] = rr;
        }
        #pragma unroll
        for (int c=0;c<C_;c++) cx[c] = cx2[c];
    }
}

// ---------------- K2: combine partials -> beta[t,b,c], thr[t,b] ----------------
__global__ __launch_bounds__(64) void combine_kernel(
    const float* __restrict__ partials,
    const float* __restrict__ att_w1,   // (1,16) row-major
    const float* __restrict__ att_w2,   // (8,1)
    const float* __restrict__ dwp, const float* __restrict__ twp,
    const float* __restrict__ mwp,
    float* __restrict__ beta_out, float* __restrict__ thr_out,
    float* __restrict__ zeropad)
{
    int tb = blockIdx.x;
    int t  = tb / B_;
    int i  = threadIdx.x;
    if (tb == 0 && i < 16) zeropad[i] = 0.f;   // 64B zero region for lif halo loads
    __shared__ float v[NV];
    if (i < NV){
        const float* p = partials + (size_t)tb*NSL*NV;
        bool mx = (i>=8 && i<16);
        float acc = p[i];
        #pragma unroll
        for (int k=1;k<NSL;k++){
            float x = p[k*NV + i];
            acc = mx ? fmaxf(acc, x) : (acc + x);
        }
        v[i] = acc;
    }
    __syncthreads();
    if (i == 0){
        float h1 = 0.f;
        for (int c=0;c<C_;c++) h1 += v[8+c] * att_w1[c];
        for (int c=0;c<C_;c++) h1 += (v[c]/(float)HW_) * att_w1[C_+c];
        h1 = fmaxf(h1, 0.f);
        float total = 0.f;
        for (int c=0;c<C_;c++) total += v[c];
        float density  = total / (float)CHW_;
        float temporal = (t==0) ? 0.f : v[16] / (float)CHW_;
        float motion   = (v[18] - v[17]/72.f) / 71.f / (float)HW_;
        float z = dwp[0]*density + twp[0]*temporal + mwp[0]*motion;
        float adj = 2.f / (1.f + expf(-z));
        thr_out[tb] = 1.f + adj;
        for (int c=0;c<C_;c++){
            float sg = 1.f / (1.f + expf(-(h1 * att_w2[c])));
            beta_out[tb*C_ + c] = 0.5f + 0.45f*sg;
        }
    }
}

// ---------------- K3: depthwise conv + sequential LIF scan (unchanged) ----------------
__device__ __forceinline__ void gload16(const float* src, float* lds_dst){
    __builtin_amdgcn_global_load_lds(
        (const __attribute__((address_space(1))) unsigned int*)src,
        (__attribute__((address_space(3))) unsigned int*)lds_dst, 16, 0, 0);
}

__device__ __forceinline__ float fast_atan(float x){
    float ax = fabsf(x);
    bool inv = ax > 1.f;
    float z  = inv ? __builtin_amdgcn_rcpf(ax) : ax;
    float z2 = z*z;
    float p = -0.0117212f;
    p = fmaf(p, z2,  0.05265332f);
    p = fmaf(p, z2, -0.11643287f);
    p = fmaf(p, z2,  0.19354346f);
    p = fmaf(p, z2, -0.33262347f);
    p = fmaf(p, z2,  0.99997726f);
    p = p * z;
    float r = inv ? (1.57079632679f - p) : p;
    return copysignf(r, x);
}

#define SROWS 10   // staged rows: h0-1 .. h0+8

__global__ __launch_bounds__(256, 8) void lif_kernel(
    const float* __restrict__ events,
    const float* __restrict__ conv_w,   // (C,1,3,3)
    const float* __restrict__ beta,     // [T*B*C]
    const float* __restrict__ thr,      // [T*B]
    const float* __restrict__ zeropad,  // >=16B of zeros
    float* __restrict__ out)
{
    int bid  = blockIdx.x;
    int hblk = bid & 15;                // 16 row-blocks of 8 rows
    int bc   = bid >> 4;                // 0..127
    int b = bc >> 3, c = bc & 7;
    int h0 = hblk * 8;
    int tid = threadIdx.x;
    int wv  = tid >> 6;                 // wave id 0..3

    float wk[9];
    #pragma unroll
    for (int k=0;k<9;k++) wk[k] = conv_w[c*9 + k];

    __shared__ float lds[2][SROWS*W_];  // 2 x 10 x 128 floats = 10 KiB

    int idxA = tid,        rowA = idxA >> 5, colA = (idxA & 31) * 4;
    int idxB = 256 + tid,  rowB = idxB >> 5, colB = (idxB & 31) * 4;
    int ghA = h0 - 1 + rowA;
    int ghB = h0 - 1 + rowB;
    bool okA = (ghA >= 0) && (ghA < H_);
    bool okB = (ghB >= 0) && (ghB < H_);
    const float* baseFrame = events + ((size_t)(b * C_) + c) * HW_;
    const float* srcA0 = okA ? (baseFrame + ghA*W_ + colA) : zeropad;
    const float* srcB0 = okB ? (baseFrame + ghB*W_ + colB) : zeropad;
    const size_t tstep = (size_t)B_ * CHW_;
    size_t stepA = okA ? tstep : 0;
    size_t stepB = okB ? tstep : 0;

    int w  = tid & 127;
    int rg = tid >> 7;
    int rbase = rg * 4;
    int wl = (w > 0)    ? w-1 : 0;
    int wr = (w < W_-1) ? w+1 : W_-1;
    bool hasL = (w > 0), hasR = (w < W_-1);

    float v[4];
    #pragma unroll
    for (int i=0;i<4;i++) v[i] = 0.f;

    gload16(srcA0, &lds[0][wv*256]);
    if (wv == 0) gload16(srcB0, &lds[0][1024]);

    const float* bp = beta + (b*C_ + c);
    const float* tp = thr + b;
    float bv = bp[0];
    float th = tp[0];

    for (int t = 0; t < T_; ++t){
        int cur = t & 1, nxt = cur ^ 1;
        __syncthreads();

        if (t + 1 < T_){
            gload16(srcA0 + (size_t)(t+1)*stepA, &lds[nxt][wv*256]);
            if (wv == 0) gload16(srcB0 + (size_t)(t+1)*stepB, &lds[nxt][1024]);
        }
        float bvn = (t+1 < T_) ? bp[(size_t)(t+1)*B_*C_] : 0.f;
        float thn = (t+1 < T_) ? tp[(size_t)(t+1)*B_]    : 0.f;

        const float* L = &lds[cur][0];
        float omb = 1.f - bv;
        float* op = out + ((size_t)(t*B_+b)*C_ + c)*HW_ + h0*W_;

        const float* row0 = L + rbase*W_;
        const float* row1 = row0 + W_;
        float la = hasL ? row0[wl] : 0.f;  float ma = row0[w];  float ra = hasR ? row0[wr] : 0.f;
        float lb = hasL ? row1[wl] : 0.f;  float mb = row1[w];  float rb = hasR ? row1[wr] : 0.f;

        #pragma unroll
        for (int i=0;i<4;i++){
            const float* rowc = L + (rbase+2+i)*W_;
            float lc = hasL ? rowc[wl] : 0.f;
            float mc = rowc[w];
            float rc = hasR ? rowc[wr] : 0.f;
            float wi = wk[0]*la + wk[1]*ma + wk[2]*ra
                     + wk[3]*lb + wk[4]*mb + wk[5]*rb
                     + wk[6]*lc + wk[7]*mc + wk[8]*rc;
            float vv = fmaf(bv, v[i], omb*wi);
            float sp = fast_atan(2.f*(vv - th))*0.5f + 0.5f;
            op[(rbase+i)*W_ + w] = mb * sp;
            v[i] = (1.f - sp) * vv;
            la=lb; ma=mb; ra=rb; lb=lc; mb=mc; rb=rc;
        }
        bv = bvn; th = thn;
    }
}

extern "C" void kernel_launch(void* const* d_in, const int* in_sizes, int n_in,
                              void* d_out, int out_size, void* d_ws, size_t ws_size,
                              hipStream_t stream)
{
    const float* events = (const float*)d_in[0];
    const float* conv_w = (const float*)d_in[1];
    const float* att_w1 = (const float*)d_in[2];
    const float* att_w2 = (const float*)d_in[3];
    const float* dwp    = (const float*)d_in[4];
    const float* twp    = (const float*)d_in[5];
    const float* mwp    = (const float*)d_in[6];
    float* out = (float*)d_out;

    float* ws       = (float*)d_ws;
    float* partials = ws;                              // 256*16*19 floats
    float* beta     = ws + (size_t)T_*B_*NSL*NV;
    float* thr      = beta + (size_t)T_*B_*C_;
    float* zeropad  = thr + T_*B_;

    stats_kernel  <<<B_*NSL*2,  256, 0, stream>>>(events, partials);
    combine_kernel<<<T_*B_,     64,  0, stream>>>(partials, att_w1, att_w2,
                                                  dwp, twp, mwp, beta, thr, zeropad);
    lif_kernel    <<<B_*C_*16,  256, 0, stream>>>(events, conv_w, beta, thr, zeropad, out);
}

// Round 6
// 99.339 us; speedup vs baseline: 1.0690x; 1.0690x over previous
//
#include <hip/hip_runtime.h>
#include <math.h>

#define T_ 16
#define B_ 16
#define C_ 8
#define H_ 128
#define W_ 128
#define HW_ (H_*W_)
#define CHW_ (C_*HW_)
#define NSLICE 8
#define SR (H_/NSLICE)               // 16 rows per slice
#define NV 19                        // 0..7 sumc, 8..15 maxc, 16 dsum, 17 m1, 18 m2

__device__ __forceinline__ float wave_sum(float v){
    #pragma unroll
    for (int o=32;o>0;o>>=1) v += __shfl_down(v,o,64);
    return v;
}
__device__ __forceinline__ float wave_max(float v){
    #pragma unroll
    for (int o=32;o>0;o>>=1) v = fmaxf(v,__shfl_down(v,o,64));
    return v;
}

// ---------------- K1: per-(t,b) row-slice statistics (R3 version) ----------------
__global__ __launch_bounds__(256) void stats_kernel(
    const float* __restrict__ events, float* __restrict__ partials)
{
    int blk = blockIdx.x;
    int s  = blk & (NSLICE-1);
    int tb = blk >> 3;
    int t  = tb >> 4;                 // / B_
    int h0 = s * SR;
    int tid = threadIdx.x;
    const float* frame = events + (size_t)tb * CHW_;
    const float* prev  = frame - (size_t)B_ * CHW_;   // only deref'd when t>0

    __shared__ float yb[SR+2][W_];    // y = sum over channels, rows h0-1 .. h0+SR
    __shared__ float red[4][NV];

    int cg = tid & 31;                // float4 column group
    int c0 = cg * 4;
    int r  = tid >> 5;                // 0..7 (row within pass)

    float cnt0 = (c0   == 0 || c0   == W_-1) ? 2.f : 3.f;
    float cnt1 = 3.f;
    float cnt2 = 3.f;
    float cnt3 = (c0+3 == 0 || c0+3 == W_-1) ? 2.f : 3.f;

    float sumc[C_], maxc[C_];
    #pragma unroll
    for (int c=0;c<C_;c++){ sumc[c]=0.f; maxc[c]=-INFINITY; }
    float dsum=0.f, m1=0.f, m2=0.f;

    // halo rows (y only): tid<32 -> row h0-1; tid in [32,64) -> row h0+SR
    if (tid < 64){
        int hr = (tid >> 5) ? SR : -1;
        int gh = h0 + hr;
        float y0=0.f,y1=0.f,y2=0.f,y3=0.f;
        if (gh >= 0 && gh < H_){
            const float* rp = frame + gh*W_ + (tid&31)*4;
            #pragma unroll
            for (int c=0;c<C_;c++){
                float4 x = *reinterpret_cast<const float4*>(rp + c*HW_);
                y0+=x.x; y1+=x.y; y2+=x.z; y3+=x.w;
            }
        }
        float* yp = &yb[hr+1][(tid&31)*4];
        yp[0]=y0; yp[1]=y1; yp[2]=y2; yp[3]=y3;
    }

    // main rows: 2 passes of 8 rows
    #pragma unroll 1
    for (int p=0;p<2;p++){
        int lr = r + 8*p;             // 0..15
        int gh = h0 + lr;
        const float* rp = frame + gh*W_ + c0;
        float4 xv[C_];
        #pragma unroll
        for (int c=0;c<C_;c++)
            xv[c] = *reinterpret_cast<const float4*>(rp + c*HW_);

        float y0=0.f,y1=0.f,y2=0.f,y3=0.f;
        float q0=0.f,q1=0.f,q2=0.f,q3=0.f;
        #pragma unroll
        for (int c=0;c<C_;c++){
            float4 x = xv[c];
            y0+=x.x; y1+=x.y; y2+=x.z; y3+=x.w;
            q0=fmaf(x.x,x.x,q0); q1=fmaf(x.y,x.y,q1);
            q2=fmaf(x.z,x.z,q2); q3=fmaf(x.w,x.w,q3);
            sumc[c] += (x.x+x.y)+(x.z+x.w);
            maxc[c] = fmaxf(maxc[c], fmaxf(fmaxf(x.x,x.y),fmaxf(x.z,x.w)));
        }
        float cnth = (gh==0 || gh==H_-1) ? 2.f : 3.f;
        m2 += cnth * (q0*cnt0 + q1*cnt1 + q2*cnt2 + q3*cnt3);

        if (t > 0){
            const float* pp = prev + gh*W_ + c0;
            #pragma unroll
            for (int c=0;c<C_;c++){
                float4 pv = *reinterpret_cast<const float4*>(pp + c*HW_);
                float4 x  = xv[c];
                dsum += fabsf(x.x-pv.x)+fabsf(x.y-pv.y)
                      + fabsf(x.z-pv.z)+fabsf(x.w-pv.w);
            }
        }
        float* yp = &yb[lr+1][c0];
        yp[0]=y0; yp[1]=y1; yp[2]=y2; yp[3]=y3;
    }
    __syncthreads();

    // box filter of y -> m1 += s1^2 ; thread: col w, 8 rows
    {
        int w  = tid & 127;
        int rg = tid >> 7;            // 0 or 1
        bool hasL = (w>0), hasR = (w<W_-1);
        int base = rg*8;              // local rows base..base+7  (yb rows base+1..base+8)
        const float* row;
        row = yb[base];   float a0 = row[w] + (hasL?row[w-1]:0.f) + (hasR?row[w+1]:0.f);
        row = yb[base+1]; float a1 = row[w] + (hasL?row[w-1]:0.f) + (hasR?row[w+1]:0.f);
        #pragma unroll
        for (int i=0;i<8;i++){
            row = yb[base+2+i];
            float a2 = row[w] + (hasL?row[w-1]:0.f) + (hasR?row[w+1]:0.f);
            float s1 = a0 + a1 + a2;
            m1 = fmaf(s1, s1, m1);
            a0 = a1; a1 = a2;
        }
    }

    // block reduce 19 quantities (4 waves)
    float vals[NV];
    #pragma unroll
    for (int c=0;c<C_;c++){ vals[c]=sumc[c]; vals[8+c]=maxc[c]; }
    vals[16]=dsum; vals[17]=m1; vals[18]=m2;

    int lane = tid & 63, wv = tid >> 6;
    #pragma unroll
    for (int i=0;i<NV;i++){
        float rr = (i>=8 && i<16) ? wave_max(vals[i]) : wave_sum(vals[i]);
        if (lane==0) red[wv][i] = rr;
    }
    __syncthreads();
    if (tid < NV){
        float a = red[0][tid], b2 = red[1][tid], c = red[2][tid], d = red[3][tid];
        float rr = (tid>=8 && tid<16) ? fmaxf(fmaxf(a,b2),fmaxf(c,d)) : ((a+b2)+(c+d));
        partials[((size_t)tb*NSLICE + s)*NV + tid] = rr;
    }
}

// ---------------- K2: combine partials -> beta[t,b,c], thr[t,b] ----------------
__global__ __launch_bounds__(64) void combine_kernel(
    const float* __restrict__ partials,
    const float* __restrict__ att_w1,   // (1,16) row-major
    const float* __restrict__ att_w2,   // (8,1)
    const float* __restrict__ dwp, const float* __restrict__ twp,
    const float* __restrict__ mwp,
    float* __restrict__ beta_out, float* __restrict__ thr_out)
{
    int tb = blockIdx.x;
    int t  = tb / B_;
    int i  = threadIdx.x;
    __shared__ float v[NV];
    if (i < NV){
        const float* p = partials + (size_t)tb*NSLICE*NV;
        bool mx = (i>=8 && i<16);
        float acc = p[i];
        #pragma unroll
        for (int k=1;k<NSLICE;k++){
            float x = p[k*NV + i];
            acc = mx ? fmaxf(acc, x) : (acc + x);
        }
        v[i] = acc;
    }
    __syncthreads();
    if (i == 0){
        float h1 = 0.f;
        for (int c=0;c<C_;c++) h1 += v[8+c] * att_w1[c];
        for (int c=0;c<C_;c++) h1 += (v[c]/(float)HW_) * att_w1[C_+c];
        h1 = fmaxf(h1, 0.f);
        float total = 0.f;
        for (int c=0;c<C_;c++) total += v[c];
        float density  = total / (float)CHW_;
        float temporal = (t==0) ? 0.f : v[16] / (float)CHW_;
        float motion   = (v[18] - v[17]/72.f) / 71.f / (float)HW_;
        float z = dwp[0]*density + twp[0]*temporal + mwp[0]*motion;
        float adj = 2.f / (1.f + expf(-z));
        thr_out[tb] = 1.f + adj;
        for (int c=0;c<C_;c++){
            float sg = 1.f / (1.f + expf(-(h1 * att_w2[c])));
            beta_out[tb*C_ + c] = 0.5f + 0.45f*sg;
        }
    }
}

// ---------------- K3: LIF with register-staged (allocating) loads ----------------
__device__ __forceinline__ float fast_atan(float x){
    float ax = fabsf(x);
    bool inv = ax > 1.f;
    float z  = inv ? __builtin_amdgcn_rcpf(ax) : ax;
    float z2 = z*z;
    float p = -0.0117212f;
    p = fmaf(p, z2,  0.05265332f);
    p = fmaf(p, z2, -0.11643287f);
    p = fmaf(p, z2,  0.19354346f);
    p = fmaf(p, z2, -0.33262347f);
    p = fmaf(p, z2,  0.99997726f);
    p = p * z;
    float r = inv ? (1.57079632679f - p) : p;
    return copysignf(r, x);
}

#define SROWS 10   // staged rows: h0-1 .. h0+8

__global__ __launch_bounds__(256, 8) void lif_kernel(
    const float* __restrict__ events,
    const float* __restrict__ conv_w,   // (C,1,3,3)
    const float* __restrict__ beta,     // [T*B*C]
    const float* __restrict__ thr,      // [T*B]
    float* __restrict__ out)
{
    int bid  = blockIdx.x;
    int hblk = bid & 15;                // 16 row-blocks of 8 rows
    int bc   = bid >> 4;                // 0..127
    int b = bc >> 3, c = bc & 7;
    int h0 = hblk * 8;
    int tid = threadIdx.x;

    float wk[9];
    #pragma unroll
    for (int k=0;k<9;k++) wk[k] = conv_w[c*9 + k];

    __shared__ float lds[2][SROWS*W_];  // 2 x 10 x 128 floats = 10 KiB

    // staging slots (float4 granularity): slotA = tid (rows 0..7),
    // slotB = 256+tid for tid<64 (rows 8..9)
    int rowA = tid >> 5,        colA = (tid & 31) * 4;
    int rowB = (256+tid) >> 5,  colB = (tid & 31) * 4;
    int ghA = h0 - 1 + rowA;
    int ghB = h0 - 1 + rowB;
    bool okA = (ghA >= 0) && (ghA < H_);
    bool okB = (tid < 64) && (ghB >= 0) && (ghB < H_);
    const float* baseFrame = events + ((size_t)(b * C_) + c) * HW_;
    const float* srcA = baseFrame + ghA*W_ + colA;   // not deref'd unless okA
    const float* srcB = baseFrame + ghB*W_ + colB;
    const size_t tstep = (size_t)B_ * CHW_;

    // compute mapping
    int w  = tid & 127;
    int rg = tid >> 7;
    int rbase = rg * 4;
    int wl = (w > 0)    ? w-1 : 0;
    int wr = (w < W_-1) ? w+1 : W_-1;
    bool hasL = (w > 0), hasR = (w < W_-1);

    float v[4];
    #pragma unroll
    for (int i=0;i<4;i++) v[i] = 0.f;

    float4 z4; z4.x=0.f; z4.y=0.f; z4.z=0.f; z4.w=0.f;

    // prologue: stage t=0 into buffer 0
    {
        float4 sa = okA ? *reinterpret_cast<const float4*>(srcA) : z4;
        float4 sb = okB ? *reinterpret_cast<const float4*>(srcB) : z4;
        *reinterpret_cast<float4*>(&lds[0][tid*4]) = sa;
        if (tid < 64) *reinterpret_cast<float4*>(&lds[0][1024 + tid*4]) = sb;
    }
    __syncthreads();

    const float* bp = beta + (b*C_ + c);
    const float* tp = thr + b;
    float bv = bp[0];
    float th = tp[0];

    for (int t = 0; t < T_; ++t){
        int cur = t & 1, nxt = cur ^ 1;

        // issue loads for t+1 early (overlap with compute below)
        float4 na = z4, nb = z4;
        if (t + 1 < T_){
            if (okA) na = *reinterpret_cast<const float4*>(srcA + (size_t)(t+1)*tstep);
            if (okB) nb = *reinterpret_cast<const float4*>(srcB + (size_t)(t+1)*tstep);
        }
        float bvn = (t+1 < T_) ? bp[(size_t)(t+1)*B_*C_] : 0.f;
        float thn = (t+1 < T_) ? tp[(size_t)(t+1)*B_]    : 0.f;

        const float* L = &lds[cur][0];
        float omb = 1.f - bv;
        float* op = out + ((size_t)(t*B_+b)*C_ + c)*HW_ + h0*W_;

        const float* row0 = L + rbase*W_;
        const float* row1 = row0 + W_;
        float la = hasL ? row0[wl] : 0.f;  float ma = row0[w];  float ra = hasR ? row0[wr] : 0.f;
        float lb = hasL ? row1[wl] : 0.f;  float mb = row1[w];  float rb = hasR ? row1[wr] : 0.f;

        #pragma unroll
        for (int i=0;i<4;i++){
            const float* rowc = L + (rbase+2+i)*W_;
            float lc = hasL ? rowc[wl] : 0.f;
            float mc = rowc[w];
            float rc = hasR ? rowc[wr] : 0.f;
            float wi = wk[0]*la + wk[1]*ma + wk[2]*ra
                     + wk[3]*lb + wk[4]*mb + wk[5]*rb
                     + wk[6]*lc + wk[7]*mc + wk[8]*rc;
            float vv = fmaf(bv, v[i], omb*wi);
            float sp = fast_atan(2.f*(vv - th))*0.5f + 0.5f;
            op[(rbase+i)*W_ + w] = mb * sp;
            v[i] = (1.f - sp) * vv;
            la=lb; ma=mb; ra=rb; lb=lc; mb=mc; rb=rc;
        }

        // write t+1 stage into the other buffer, then single barrier
        if (t + 1 < T_){
            *reinterpret_cast<float4*>(&lds[nxt][tid*4]) = na;
            if (tid < 64) *reinterpret_cast<float4*>(&lds[nxt][1024 + tid*4]) = nb;
        }
        __syncthreads();

        bv = bvn; th = thn;
    }
}

extern "C" void kernel_launch(void* const* d_in, const int* in_sizes, int n_in,
                              void* d_out, int out_size, void* d_ws, size_t ws_size,
                              hipStream_t stream)
{
    const float* events = (const float*)d_in[0];
    const float* conv_w = (const float*)d_in[1];
    const float* att_w1 = (const float*)d_in[2];
    const float* att_w2 = (const float*)d_in[3];
    const float* dwp    = (const float*)d_in[4];
    const float* twp    = (const float*)d_in[5];
    const float* mwp    = (const float*)d_in[6];
    float* out = (float*)d_out;

    float* ws       = (float*)d_ws;
    float* partials = ws;                              // 256*8*19 floats
    float* beta     = ws + (size_t)T_*B_*NSLICE*NV;
    float* thr      = beta + (size_t)T_*B_*C_;

    stats_kernel  <<<T_*B_*NSLICE, 256, 0, stream>>>(events, partials);
    combine_kernel<<<T_*B_,        64,  0, stream>>>(partials, att_w1, att_w2,
                                                     dwp, twp, mwp, beta, thr);
    lif_kernel    <<<B_*C_*16,     256, 0, stream>>>(events, conv_w, beta, thr, out);
}